// Round 2
// baseline (406.909 us; speedup 1.0000x reference)
//
#include <hip/hip_runtime.h>
#include <hip/hip_fp16.h>

typedef unsigned short u16;
typedef unsigned int   u32;
typedef __bf16 bf16x8 __attribute__((ext_vector_type(8)));
typedef float  f32x4  __attribute__((ext_vector_type(4)));

// ---------------- problem constants ----------------
constexpr int BB   = 16;            // batch
constexpr int S    = 4096;          // seq len
constexpr int M    = BB * S;        // 65536 rows
constexpr int DIN  = 64;
constexpr int H    = 512;
constexpr int DI   = 768;
constexpr int N2   = 1536;          // 2*DI
constexpr int CL   = 128;           // chunk length
constexpr int NCHB = S / CL;        // 32 chunks per batch
constexpr int NCHUNK = M / CL;      // 512 chunks total
constexpr int DTILES = 12;          // 768 d / 64 d per tile

// ---------------- workspace layout (bytes) — total 16,453,632 (~16.5 MB) ----
constexpr size_t OFF_XB   = 0;                     // u16 [65536][64]  = 8388608
constexpr size_t OFF_B2C  = 8388608;               // u16 [1536][64]   = 196608
constexpr size_t OFF_WC   = 8585216;               // f32 [768] (pad 4096)
constexpr size_t OFF_CC   = 8589312;               // f32 [512][768]   = 1572864
constexpr size_t OFF_HE   = OFF_CC  + 1572864;
constexpr size_t OFF_HIN  = OFF_HE  + 1572864;
constexpr size_t OFF_PART = OFF_HIN + 1572864;     // f32 [12][65536]  = 3145728

__device__ __forceinline__ u16 f2bf(float f) {
  u32 u = __float_as_uint(f);
  u32 r = (u + 0x7FFFu + ((u >> 16) & 1u)) >> 16;
  return (u16)r;
}

// ---------------- prep: x f32 -> bf16 ----------------
__global__ __launch_bounds__(256) void prep_xb(const float* __restrict__ x,
                                               u16* __restrict__ xb) {
  size_t i = (size_t)(blockIdx.x * 256 + threadIdx.x) * 8;   // 4194304 elems
  float4 f0 = *(const float4*)(x + i);
  float4 f1 = *(const float4*)(x + i + 4);
  u32 w0 = f2bf(f0.x) | ((u32)f2bf(f0.y) << 16);
  u32 w1 = f2bf(f0.z) | ((u32)f2bf(f0.w) << 16);
  u32 w2 = f2bf(f1.x) | ((u32)f2bf(f1.y) << 16);
  u32 w3 = f2bf(f1.z) | ((u32)f2bf(f1.w) << 16);
  uint4 o = make_uint4(w0, w1, w2, w3);
  *(uint4*)(xb + i) = o;
}

// ---------------- prep: B2c[n][k] = bf16( (W_in @ W_hg)[k][pi(n)] ) --------
// pi: n = 32g + r : r<16 -> hidden col (16g+r) ; r>=16 -> gate col (768+16g+(r-16))
__global__ __launch_bounds__(256) void prep_b2c(const float* __restrict__ Win,
                                                const float* __restrict__ Whg,
                                                u16* __restrict__ B2c) {
  int idx = blockIdx.x * 256 + threadIdx.x;   // 98304 = 1536*64
  int k = idx & 63, n = idx >> 6;
  int g = n >> 5, r = n & 31;
  int col = (r < 16) ? (g * 16 + r) : (DI + g * 16 + (r - 16));
  float acc = 0.f;
  for (int j = 0; j < H; ++j)
    acc += Win[k * H + j] * Whg[(size_t)j * N2 + col];
  B2c[idx] = f2bf(acc);
}

// ---------------- prep: wcomb[d] = W_out[d,:] . W_final ----------------
__global__ __launch_bounds__(256) void prep_wcomb(const float* __restrict__ Wout,
                                                  const float* __restrict__ Wfin,
                                                  float* __restrict__ wc) {
  int wv = threadIdx.x >> 6, ln = threadIdx.x & 63;
  int d = blockIdx.x * 4 + wv;                // 192 blocks -> 768 d
  const float* row = Wout + (size_t)d * H;
  float s = 0.f;
  #pragma unroll
  for (int j = 0; j < 8; ++j) {
    int k = j * 64 + ln;
    s += row[k] * Wfin[k];
  }
  #pragma unroll
  for (int off = 32; off; off >>= 1) s += __shfl_xor(s, off);
  if (ln == 0) wc[d] = s;
}

// -------- fused: GEMM(K=64) + activation + chunk-local scan --------
// PASS 1: emit per-chunk summaries (Cc = prod c, He = local h end)
// PASS 2: carried scan + fused wcomb dot -> partial predictions
template<int PASS>
__global__ __launch_bounds__(256) void fused_gemm_scan(
    const u16* __restrict__ xb, const u16* __restrict__ B2c,
    const float* __restrict__ Hin, const float* __restrict__ wcomb,
    float* __restrict__ Cc, float* __restrict__ He,
    float* __restrict__ part) {
  __shared__ __align__(16) u16 AB[16384];     // A tile [0..8191], B tile [8192..]
  __shared__ float sout[CL];
  u32* cvl = (u32*)AB;                        // repurposed after barrier: [128][64]

  const int tid = threadIdx.x, wv = tid >> 6, ln = tid & 63;
  const int nt = blockIdx.x % DTILES, ck = blockIdx.x / DTILES;
  const int m0 = ck * CL;
  const int wr = wv >> 1, wcol = wv & 1;
  const int lrow = ln & 15, lk = (ln >> 4) * 8;

  // stage A (128x64 bf16, contiguous 16KB) and B (128x64 bf16, contiguous)
  {
    const uint4* gA = (const uint4*)(xb + (size_t)m0 * 64);
    const uint4* gB = (const uint4*)(B2c + (size_t)nt * 128 * 64);
    uint4* lA = (uint4*)AB;
    uint4* lB = (uint4*)(AB + 8192);
    #pragma unroll
    for (int j = 0; j < 4; ++j) {
      int q = j * 256 + tid;                  // 0..1023 x 16B
      lA[q] = gA[q];
      lB[q] = gB[q];
    }
  }
  __syncthreads();

  f32x4 acc[4][4] = {};
  const u16* Al = AB;
  const u16* Bl = AB + 8192;
  #pragma unroll
  for (int kk = 0; kk < 2; ++kk) {
    bf16x8 af[4], bfr[4];
    #pragma unroll
    for (int i = 0; i < 4; ++i)
      af[i] = *(const bf16x8*)&Al[(wr * 64 + i * 16 + lrow) * 64 + kk * 32 + lk];
    #pragma unroll
    for (int j = 0; j < 4; ++j)
      bfr[j] = *(const bf16x8*)&Bl[(wcol * 64 + j * 16 + lrow) * 64 + kk * 32 + lk];
    #pragma unroll
    for (int i = 0; i < 4; ++i)
      #pragma unroll
      for (int j = 0; j < 4; ++j)
        acc[i][j] = __builtin_amdgcn_mfma_f32_16x16x32_bf16(af[i], bfr[j], acc[i][j], 0, 0, 0);
  }
  __syncthreads();   // all LDS reads done -> safe to overwrite tile as cvl

  // activation; fragment pair (2jp, 2jp+1) = (hidden, gate) of the SAME d
  #pragma unroll
  for (int i = 0; i < 4; ++i)
    #pragma unroll
    for (int jp = 0; jp < 2; ++jp) {
      f32x4 hid = acc[i][2 * jp + 0];
      f32x4 gat = acc[i][2 * jp + 1];
      const int dl = (wcol * 2 + jp) * 16 + lrow;   // 0..63
      #pragma unroll
      for (int r = 0; r < 4; ++r) {
        int row = wr * 64 + i * 16 + (ln >> 4) * 4 + r;   // 0..127
        float gate = gat[r], hidden = hid[r];
        float eg  = __expf(gate);
        float cc  = 1.0f / (1.0f + eg);          // sigmoid(-gate) = 1 - z
        float zz  = eg * cc;                     // sigmoid(gate)  = z
        float gg  = (hidden >= 0.0f) ? (hidden + 0.5f)
                                     : (1.0f / (1.0f + __expf(-hidden)));
        float vv  = zz * gg;
        __half2 p = __floats2half2_rn(cc, vv);
        cvl[row * 64 + dl] = *(const u32*)&p;
      }
    }
  __syncthreads();

  if (tid < 64) {                               // wave 0 scans 64 channels
    const int d = tid;
    if (PASS == 1) {
      float hl = 0.f, pr = 1.f;
      for (int t = 0; t < CL; ++t) {
        u32 u = cvl[t * 64 + d];
        __half2 hv = *(const __half2*)&u;
        float2 f = __half22float2(hv);
        hl = fmaf(f.x, hl, f.y);
        pr *= f.x;
      }
      int idx = ck * DI + nt * 64 + d;
      Cc[idx] = pr;
      He[idx] = hl;
    } else {
      float hh = Hin[ck * DI + nt * 64 + d];
      float wd = wcomb[nt * 64 + d];
      for (int t = 0; t < CL; ++t) {
        u32 u = cvl[t * 64 + d];
        __half2 hv = *(const __half2*)&u;
        float2 f = __half22float2(hv);
        hh = fmaf(f.x, hh, f.y);
        float pv = hh * wd;
        #pragma unroll
        for (int off = 32; off; off >>= 1) pv += __shfl_xor(pv, off);
        if (tid == 0) sout[t] = pv;
      }
    }
  }
  if (PASS == 2) {
    __syncthreads();
    if (tid < CL) part[(size_t)nt * M + m0 + tid] = sout[tid];
  }
}

// ---------------- cross-chunk carry scan ----------------
__global__ __launch_bounds__(768) void scan_carry(const float* __restrict__ Cc,
                                                  const float* __restrict__ He,
                                                  float* __restrict__ Hin) {
  const int b = blockIdx.x, d = threadIdx.x;
  float carry = 0.f;
  for (int q = 0; q < NCHB; ++q) {
    int idx = (b * NCHB + q) * DI + d;
    Hin[idx] = carry;
    carry = fmaf(Cc[idx], carry, He[idx]);
  }
}

// ---------------- final: sum 12 d-tile partials ----------------
__global__ __launch_bounds__(256) void reduce12(const float* __restrict__ part,
                                                float* __restrict__ out) {
  int i = blockIdx.x * 256 + threadIdx.x;     // 65536
  float s = 0.f;
  #pragma unroll
  for (int w = 0; w < DTILES; ++w) s += part[(size_t)w * M + i];
  out[i] = s;
}

// ---------------- launcher ----------------
extern "C" void kernel_launch(void* const* d_in, const int* in_sizes, int n_in,
                              void* d_out, int out_size, void* d_ws, size_t ws_size,
                              hipStream_t stream) {
  const float* x    = (const float*)d_in[0];
  const float* Win  = (const float*)d_in[1];
  const float* Whg  = (const float*)d_in[2];
  const float* Wout = (const float*)d_in[3];
  const float* Wfin = (const float*)d_in[4];
  float* out = (float*)d_out;
  char* ws = (char*)d_ws;

  u16*   xb   = (u16*)(ws + OFF_XB);
  u16*   B2c  = (u16*)(ws + OFF_B2C);
  float* wc   = (float*)(ws + OFF_WC);
  float* Cc   = (float*)(ws + OFF_CC);
  float* He   = (float*)(ws + OFF_HE);
  float* Hin  = (float*)(ws + OFF_HIN);
  float* part = (float*)(ws + OFF_PART);

  prep_xb   <<<2048, 256, 0, stream>>>(x, xb);
  prep_b2c  <<<384,  256, 0, stream>>>(Win, Whg, B2c);
  prep_wcomb<<<192,  256, 0, stream>>>(Wout, Wfin, wc);
  fused_gemm_scan<1><<<NCHUNK * DTILES, 256, 0, stream>>>(xb, B2c, Hin, wc, Cc, He, part);
  scan_carry<<<BB, DI, 0, stream>>>(Cc, He, Hin);
  fused_gemm_scan<2><<<NCHUNK * DTILES, 256, 0, stream>>>(xb, B2c, Hin, wc, Cc, He, part);
  reduce12  <<<256,  256, 0, stream>>>(part, out);
}

// Round 3
// 184.514 us; speedup vs baseline: 2.2053x; 2.2053x over previous
//
#include <hip/hip_runtime.h>
#include <hip/hip_fp16.h>

typedef unsigned short u16;
typedef unsigned int   u32;
typedef __bf16 bf16x8 __attribute__((ext_vector_type(8)));
typedef float  f32x4  __attribute__((ext_vector_type(4)));

// ---------------- problem constants ----------------
constexpr int BB   = 16;            // batch
constexpr int S    = 4096;          // seq len
constexpr int M    = BB * S;        // 65536 rows
constexpr int DIN  = 64;
constexpr int H    = 512;
constexpr int DI   = 768;
constexpr int N2   = 1536;          // 2*DI
constexpr int CL   = 128;           // chunk length
constexpr int NCHB = S / CL;        // 32 chunks per batch
constexpr int NCHUNK = M / CL;      // 512 chunks total
constexpr int DTILES = 12;          // 768 d / 64 d per tile

// ---------------- workspace layout (bytes) — total ~16.5 MB ----------------
constexpr size_t OFF_XB   = 0;                     // u16 [65536][64]  = 8388608
constexpr size_t OFF_B2C  = 8388608;               // u16 [1536][64]   = 196608
constexpr size_t OFF_WC   = 8585216;               // f32 [768] (pad 4096)
constexpr size_t OFF_CC   = 8589312;               // f32 [512][768]   = 1572864
constexpr size_t OFF_HE   = OFF_CC  + 1572864;
constexpr size_t OFF_HIN  = OFF_HE  + 1572864;
constexpr size_t OFF_PART = OFF_HIN + 1572864;     // f32 [12][65536]  = 3145728

__device__ __forceinline__ u16 f2bf(float f) {
  u32 u = __float_as_uint(f);
  u32 r = (u + 0x7FFFu + ((u >> 16) & 1u)) >> 16;
  return (u16)r;
}

// ---------------- prep: x f32 -> bf16 ----------------
__global__ __launch_bounds__(256) void prep_xb(const float* __restrict__ x,
                                               u16* __restrict__ xb) {
  size_t i = (size_t)(blockIdx.x * 256 + threadIdx.x) * 8;   // 4194304 elems
  float4 f0 = *(const float4*)(x + i);
  float4 f1 = *(const float4*)(x + i + 4);
  u32 w0 = f2bf(f0.x) | ((u32)f2bf(f0.y) << 16);
  u32 w1 = f2bf(f0.z) | ((u32)f2bf(f0.w) << 16);
  u32 w2 = f2bf(f1.x) | ((u32)f2bf(f1.y) << 16);
  u32 w3 = f2bf(f1.z) | ((u32)f2bf(f1.w) << 16);
  uint4 o = make_uint4(w0, w1, w2, w3);
  *(uint4*)(xb + i) = o;
}

// ---------------- prep: B2c[n][k] = bf16( (W_in @ W_hg)[k][pi(n)] ) --------
// pi: n = 32g + r : r<16 -> hidden col (16g+r) ; r>=16 -> gate col (768+16g+(r-16))
// LDS-staged: Win chunks [64 k][64 j] (+1 pad), coalesced loads.
__global__ __launch_bounds__(256) void prep_b2c(const float* __restrict__ Win,
                                                const float* __restrict__ Whg,
                                                u16* __restrict__ B2c) {
  __shared__ float Wl[64][65];
  const int tid = threadIdx.x;
  const int k = tid & 63;                     // for compute
  const int nloc = tid >> 6;                  // 0..3
  const int n = blockIdx.x * 4 + nloc;        // 384 blocks -> 1536 n
  const int g = n >> 5, r = n & 31;
  const int col = (r < 16) ? (g * 16 + r) : (DI + g * 16 + (r - 16));
  float acc = 0.f;
  for (int jc = 0; jc < H; jc += 64) {
    // stage: thread loads 16 rows, coalesced in j
    const int jl = tid & 63, k0 = tid >> 6;
    #pragma unroll
    for (int s = 0; s < 16; ++s) {
      int kr = k0 + 4 * s;
      Wl[kr][jl] = Win[kr * H + jc + jl];
    }
    __syncthreads();
    #pragma unroll 8
    for (int j = 0; j < 64; ++j)
      acc = fmaf(Wl[k][j], Whg[(size_t)(jc + j) * N2 + col], acc);
    __syncthreads();
  }
  B2c[n * 64 + k] = f2bf(acc);
}

// ---------------- prep: wcomb[d] = W_out[d,:] . W_final ----------------
__global__ __launch_bounds__(256) void prep_wcomb(const float* __restrict__ Wout,
                                                  const float* __restrict__ Wfin,
                                                  float* __restrict__ wc) {
  int wv = threadIdx.x >> 6, ln = threadIdx.x & 63;
  int d = blockIdx.x * 4 + wv;                // 192 blocks -> 768 d
  const float* row = Wout + (size_t)d * H;
  float s = 0.f;
  #pragma unroll
  for (int j = 0; j < 8; ++j) {
    int k = j * 64 + ln;
    s += row[k] * Wfin[k];
  }
  #pragma unroll
  for (int off = 32; off; off >>= 1) s += __shfl_xor(s, off);
  if (ln == 0) wc[d] = s;
}

// -------- fused: GEMM(K=64) + activation + chunk scan, all-wave parallel ----
// PASS 1: per-chunk summaries (Cc = prod c, He = local h end)
// PASS 2: carried scan + fused wcomb dot -> partial predictions
template<int PASS>
__global__ __launch_bounds__(256) void fused_gemm_scan(
    const u16* __restrict__ xb, const u16* __restrict__ B2c,
    const float* __restrict__ Hin, const float* __restrict__ wcomb,
    float* __restrict__ Cc, float* __restrict__ He,
    float* __restrict__ part) {
  __shared__ __align__(16) u16 AB[16384];     // A [0..8191], B [8192..]; later cvl [128][64] u32
  __shared__ float SC[4][64], SV[4][64];
  u32* cvl = (u32*)AB;

  const int tid = threadIdx.x, wv = tid >> 6, ln = tid & 63;
  const int nt = blockIdx.x % DTILES, ck = blockIdx.x / DTILES;
  const int m0 = ck * CL;
  const int wr = wv >> 1, wcol = wv & 1;
  const int lrow = ln & 15, lk = (ln >> 4) * 8;

  // stage A (128x64 bf16) and B (128x64 bf16), both contiguous 16KB
  {
    const uint4* gA = (const uint4*)(xb + (size_t)m0 * 64);
    const uint4* gB = (const uint4*)(B2c + (size_t)nt * 128 * 64);
    uint4* lA = (uint4*)AB;
    uint4* lB = (uint4*)(AB + 8192);
    #pragma unroll
    for (int j = 0; j < 4; ++j) {
      int q = j * 256 + tid;
      lA[q] = gA[q];
      lB[q] = gB[q];
    }
  }
  __syncthreads();

  f32x4 acc[4][4] = {};
  {
    const u16* Al = AB;
    const u16* Bl = AB + 8192;
    #pragma unroll
    for (int kk = 0; kk < 2; ++kk) {
      bf16x8 af[4], bfr[4];
      #pragma unroll
      for (int i = 0; i < 4; ++i)
        af[i] = *(const bf16x8*)&Al[(wr * 64 + i * 16 + lrow) * 64 + kk * 32 + lk];
      #pragma unroll
      for (int j = 0; j < 4; ++j)
        bfr[j] = *(const bf16x8*)&Bl[(wcol * 64 + j * 16 + lrow) * 64 + kk * 32 + lk];
      #pragma unroll
      for (int i = 0; i < 4; ++i)
        #pragma unroll
        for (int j = 0; j < 4; ++j)
          acc[i][j] = __builtin_amdgcn_mfma_f32_16x16x32_bf16(af[i], bfr[j], acc[i][j], 0, 0, 0);
    }
  }
  __syncthreads();   // LDS reads done -> safe to overwrite tile as cvl

  // activation; fragment pair (2jp, 2jp+1) = (hidden, gate) of the SAME d
  #pragma unroll
  for (int i = 0; i < 4; ++i)
    #pragma unroll
    for (int jp = 0; jp < 2; ++jp) {
      f32x4 hid = acc[i][2 * jp + 0];
      f32x4 gat = acc[i][2 * jp + 1];
      const int dl = (wcol * 2 + jp) * 16 + lrow;   // 0..63
      #pragma unroll
      for (int r = 0; r < 4; ++r) {
        int row = wr * 64 + i * 16 + (ln >> 4) * 4 + r;   // 0..127
        float gate = gat[r], hidden = hid[r];
        float eg  = __expf(gate);
        float cc  = 1.0f / (1.0f + eg);          // sigmoid(-gate) = 1 - z
        float zz  = eg * cc;                     // sigmoid(gate)  = z
        float gg  = (hidden >= 0.0f) ? (hidden + 0.5f)
                                     : (1.0f / (1.0f + __expf(-hidden)));
        float vv  = zz * gg;
        __half2 p = __floats2half2_rn(cc, vv);
        cvl[row * 64 + dl] = *(const u32*)&p;
      }
    }
  __syncthreads();

  // ---- segment scan: seg = wave (32 rows), d = lane ----
  float Cp = 1.f, Vp = 0.f;
  #pragma unroll 8
  for (int tt = 0; tt < 32; ++tt) {
    u32 u = cvl[(wv * 32 + tt) * 64 + ln];
    __half2 hv = *(const __half2*)&u;
    float2 f = __half22float2(hv);
    Vp = fmaf(f.x, Vp, f.y);
    Cp *= f.x;
  }
  SC[wv][ln] = Cp;
  SV[wv][ln] = Vp;
  __syncthreads();

  if (PASS == 1) {
    if (wv == 0) {
      float C = SC[0][ln], V = SV[0][ln];
      #pragma unroll
      for (int s = 1; s < 4; ++s) {
        V = fmaf(SC[s][ln], V, SV[s][ln]);
        C *= SC[s][ln];
      }
      int idx = ck * DI + nt * 64 + ln;
      Cc[idx] = C;
      He[idx] = V;
    }
  } else {
    // carry-in for this wave's segment
    float h = Hin[ck * DI + nt * 64 + ln];
    if (wv >= 1) h = fmaf(SC[0][ln], h, SV[0][ln]);
    if (wv >= 2) h = fmaf(SC[1][ln], h, SV[1][ln]);
    if (wv >= 3) h = fmaf(SC[2][ln], h, SV[2][ln]);
    const float wd = wcomb[nt * 64 + ln];
    // apply + in-place rotated pv store (same-wave rows: read precedes write)
    #pragma unroll 4
    for (int tt = 0; tt < 32; ++tt) {
      const int t = wv * 32 + tt;
      u32 u = cvl[t * 64 + ln];
      __half2 hv = *(const __half2*)&u;
      float2 f = __half22float2(hv);
      h = fmaf(f.x, h, f.y);
      float pv = h * wd;
      cvl[t * 64 + ((ln + t) & 63)] = __float_as_uint(pv);
    }
    __syncthreads();
    // row reduction: 2 threads per row, rotated (conflict-free) reads
    const int row = tid >> 1, half = tid & 1;
    float s = 0.f;
    #pragma unroll 8
    for (int jj = 0; jj < 32; ++jj) {
      int idx = (half * 32 + jj + row) & 63;
      s += __uint_as_float(cvl[row * 64 + idx]);
    }
    s += __shfl_xor(s, 1);
    if (half == 0) part[(size_t)nt * M + m0 + row] = s;
  }
}

// ---------------- cross-chunk carry scan ----------------
__global__ __launch_bounds__(768) void scan_carry(const float* __restrict__ Cc,
                                                  const float* __restrict__ He,
                                                  float* __restrict__ Hin) {
  const int b = blockIdx.x, d = threadIdx.x;
  float carry = 0.f;
  for (int q = 0; q < NCHB; ++q) {
    int idx = (b * NCHB + q) * DI + d;
    Hin[idx] = carry;
    carry = fmaf(Cc[idx], carry, He[idx]);
  }
}

// ---------------- final: sum 12 d-tile partials ----------------
__global__ __launch_bounds__(256) void reduce12(const float* __restrict__ part,
                                                float* __restrict__ out) {
  int i = blockIdx.x * 256 + threadIdx.x;     // 65536
  float s = 0.f;
  #pragma unroll
  for (int w = 0; w < DTILES; ++w) s += part[(size_t)w * M + i];
  out[i] = s;
}

// ---------------- launcher ----------------
extern "C" void kernel_launch(void* const* d_in, const int* in_sizes, int n_in,
                              void* d_out, int out_size, void* d_ws, size_t ws_size,
                              hipStream_t stream) {
  const float* x    = (const float*)d_in[0];
  const float* Win  = (const float*)d_in[1];
  const float* Whg  = (const float*)d_in[2];
  const float* Wout = (const float*)d_in[3];
  const float* Wfin = (const float*)d_in[4];
  float* out = (float*)d_out;
  char* ws = (char*)d_ws;

  u16*   xb   = (u16*)(ws + OFF_XB);
  u16*   B2c  = (u16*)(ws + OFF_B2C);
  float* wc   = (float*)(ws + OFF_WC);
  float* Cc   = (float*)(ws + OFF_CC);
  float* He   = (float*)(ws + OFF_HE);
  float* Hin  = (float*)(ws + OFF_HIN);
  float* part = (float*)(ws + OFF_PART);

  prep_xb   <<<2048, 256, 0, stream>>>(x, xb);
  prep_b2c  <<<384,  256, 0, stream>>>(Win, Whg, B2c);
  prep_wcomb<<<192,  256, 0, stream>>>(Wout, Wfin, wc);
  fused_gemm_scan<1><<<NCHUNK * DTILES, 256, 0, stream>>>(xb, B2c, Hin, wc, Cc, He, part);
  scan_carry<<<BB, DI, 0, stream>>>(Cc, He, Hin);
  fused_gemm_scan<2><<<NCHUNK * DTILES, 256, 0, stream>>>(xb, B2c, Hin, wc, Cc, He, part);
  reduce12  <<<256,  256, 0, stream>>>(part, out);
}

// Round 4
// 149.939 us; speedup vs baseline: 2.7138x; 1.2306x over previous
//
#include <hip/hip_runtime.h>
#include <hip/hip_fp16.h>

typedef unsigned short u16;
typedef unsigned int   u32;
typedef __bf16 bf16x8 __attribute__((ext_vector_type(8)));
typedef float  f32x4  __attribute__((ext_vector_type(4)));

// ---------------- problem constants ----------------
constexpr int BB   = 16;            // batch
constexpr int S    = 4096;          // seq len
constexpr int M    = BB * S;        // 65536 rows
constexpr int DIN  = 64;
constexpr int H    = 512;
constexpr int DI   = 768;
constexpr int N2   = 1536;          // 2*DI
constexpr int CL   = 128;           // chunk length
constexpr int NCHB = S / CL;        // 32 chunks per batch
constexpr int NCHUNK = M / CL;      // 512 chunks total
constexpr int DTILES = 12;          // 768 d / 64 d per tile

// ---------------- workspace layout (bytes) — total ~16.5 MB ----------------
constexpr size_t OFF_XB   = 0;                     // u16 [65536][64]  = 8388608
constexpr size_t OFF_B2C  = 8388608;               // u16 [1536][64]   = 196608
constexpr size_t OFF_WC   = 8585216;               // f32 [768] (pad 4096)
constexpr size_t OFF_CC   = 8589312;               // f32 [512][768]   = 1572864
constexpr size_t OFF_HE   = OFF_CC  + 1572864;
constexpr size_t OFF_HIN  = OFF_HE  + 1572864;
constexpr size_t OFF_PART = OFF_HIN + 1572864;     // f32 [12][65536]  = 3145728

constexpr float L2E = 1.4426950408889634f;

__device__ __forceinline__ u16 f2bf(float f) {
  u32 u = __float_as_uint(f);
  u32 r = (u + 0x7FFFu + ((u >> 16) & 1u)) >> 16;
  return (u16)r;
}

// swizzled cvl slot: kills the 4-way bank conflict on activation stores
__device__ __forceinline__ int cvs(int row, int d) {
  return row * 64 + (d ^ (((row >> 2) & 3) << 4));
}

// ---------------- prep: x f32 -> bf16 ----------------
__global__ __launch_bounds__(256) void prep_xb(const float* __restrict__ x,
                                               u16* __restrict__ xb) {
  size_t i = (size_t)(blockIdx.x * 256 + threadIdx.x) * 8;   // 4194304 elems
  float4 f0 = *(const float4*)(x + i);
  float4 f1 = *(const float4*)(x + i + 4);
  u32 w0 = f2bf(f0.x) | ((u32)f2bf(f0.y) << 16);
  u32 w1 = f2bf(f0.z) | ((u32)f2bf(f0.w) << 16);
  u32 w2 = f2bf(f1.x) | ((u32)f2bf(f1.y) << 16);
  u32 w3 = f2bf(f1.z) | ((u32)f2bf(f1.w) << 16);
  uint4 o = make_uint4(w0, w1, w2, w3);
  *(uint4*)(xb + i) = o;
}

// ---------------- prep: B2c[n][k] = bf16( (W_in @ W_hg)[k][pi(n)] ) --------
// pi: n = 32g + r : r<16 -> hidden col (16g+r) ; r>=16 -> gate col (768+16g+(r-16))
__global__ __launch_bounds__(256) void prep_b2c(const float* __restrict__ Win,
                                                const float* __restrict__ Whg,
                                                u16* __restrict__ B2c) {
  __shared__ float Wl[64][65];
  const int tid = threadIdx.x;
  const int k = tid & 63;
  const int nloc = tid >> 6;                  // 0..3
  const int n = blockIdx.x * 4 + nloc;        // 384 blocks -> 1536 n
  const int g = n >> 5, r = n & 31;
  const int col = (r < 16) ? (g * 16 + r) : (DI + g * 16 + (r - 16));
  float acc = 0.f;
  for (int jc = 0; jc < H; jc += 64) {
    const int jl = tid & 63, k0 = tid >> 6;
    #pragma unroll
    for (int s = 0; s < 16; ++s) {
      int kr = k0 + 4 * s;
      Wl[kr][jl] = Win[kr * H + jc + jl];
    }
    __syncthreads();
    #pragma unroll 8
    for (int j = 0; j < 64; ++j)
      acc = fmaf(Wl[k][j], Whg[(size_t)(jc + j) * N2 + col], acc);
    __syncthreads();
  }
  B2c[n * 64 + k] = f2bf(acc);
}

// ---------------- prep: wcomb[d] = W_out[d,:] . W_final ----------------
__global__ __launch_bounds__(256) void prep_wcomb(const float* __restrict__ Wout,
                                                  const float* __restrict__ Wfin,
                                                  float* __restrict__ wc) {
  int wv = threadIdx.x >> 6, ln = threadIdx.x & 63;
  int d = blockIdx.x * 4 + wv;                // 192 blocks -> 768 d
  const float* row = Wout + (size_t)d * H;
  float s = 0.f;
  #pragma unroll
  for (int j = 0; j < 8; ++j) {
    int k = j * 64 + ln;
    s += row[k] * Wfin[k];
  }
  #pragma unroll
  for (int off = 32; off; off >>= 1) s += __shfl_xor(s, off);
  if (ln == 0) wc[d] = s;
}

// -------- fused: GEMM(K=64) + activation + chunk scan, all-wave parallel ----
// PASS 1: per-chunk summaries (Cc = prod c, He = local h end)
// PASS 2: carried scan + fused wcomb dot -> partial predictions
template<int PASS>
__global__ __launch_bounds__(256) void fused_gemm_scan(
    const u16* __restrict__ xb, const u16* __restrict__ B2c,
    const float* __restrict__ Hin, const float* __restrict__ wcomb,
    float* __restrict__ Cc, float* __restrict__ He,
    float* __restrict__ part) {
  __shared__ __align__(16) u16 AB[16384];     // A [0..8191], B [8192..]; later cvl [128][64] u32
  __shared__ float SC[4][64], SV[4][64];
  u32* cvl = (u32*)AB;

  const int tid = threadIdx.x, wv = tid >> 6, ln = tid & 63;
  const int nt = blockIdx.x % DTILES, ck = blockIdx.x / DTILES;
  const int m0 = ck * CL;
  const int wr = wv >> 1, wcol = wv & 1;
  const int lrow = ln & 15, lk = (ln >> 4) * 8;

  // stage A (128x64 bf16) and B (128x64 bf16), both contiguous 16KB
  {
    const uint4* gA = (const uint4*)(xb + (size_t)m0 * 64);
    const uint4* gB = (const uint4*)(B2c + (size_t)nt * 128 * 64);
    uint4* lA = (uint4*)AB;
    uint4* lB = (uint4*)(AB + 8192);
    #pragma unroll
    for (int j = 0; j < 4; ++j) {
      int q = j * 256 + tid;
      lA[q] = gA[q];
      lB[q] = gB[q];
    }
  }
  __syncthreads();

  f32x4 acc[4][4] = {};
  {
    const u16* Al = AB;
    const u16* Bl = AB + 8192;
    #pragma unroll
    for (int kk = 0; kk < 2; ++kk) {
      bf16x8 af[4], bfr[4];
      #pragma unroll
      for (int i = 0; i < 4; ++i)
        af[i] = *(const bf16x8*)&Al[(wr * 64 + i * 16 + lrow) * 64 + kk * 32 + lk];
      #pragma unroll
      for (int j = 0; j < 4; ++j)
        bfr[j] = *(const bf16x8*)&Bl[(wcol * 64 + j * 16 + lrow) * 64 + kk * 32 + lk];
      #pragma unroll
      for (int i = 0; i < 4; ++i)
        #pragma unroll
        for (int j = 0; j < 4; ++j)
          acc[i][j] = __builtin_amdgcn_mfma_f32_16x16x32_bf16(af[i], bfr[j], acc[i][j], 0, 0, 0);
    }
  }
  __syncthreads();   // LDS reads done -> safe to overwrite tile as cvl

  // activation; fragment pair (2jp, 2jp+1) = (hidden, gate) of the SAME d
  #pragma unroll
  for (int i = 0; i < 4; ++i)
    #pragma unroll
    for (int jp = 0; jp < 2; ++jp) {
      f32x4 hid = acc[i][2 * jp + 0];
      f32x4 gat = acc[i][2 * jp + 1];
      const int dl = (wcol * 2 + jp) * 16 + lrow;   // 0..63
      #pragma unroll
      for (int r = 0; r < 4; ++r) {
        int row = wr * 64 + i * 16 + (ln >> 4) * 4 + r;   // 0..127
        float gate = gat[r], hidden = hid[r];
        float eg  = __builtin_amdgcn_exp2f(gate * L2E);
        float cc  = __builtin_amdgcn_rcpf(1.0f + eg);     // sigmoid(-gate)
        float zz  = eg * cc;                              // sigmoid(gate)
        float gneg = __builtin_amdgcn_rcpf(
                        1.0f + __builtin_amdgcn_exp2f(-hidden * L2E));
        float gg  = (hidden >= 0.0f) ? (hidden + 0.5f) : gneg;
        float vv  = zz * gg;
        __half2 p = __floats2half2_rn(cc, vv);
        cvl[cvs(row, dl)] = *(const u32*)&p;
      }
    }
  __syncthreads();

  // ---- segment scan: seg = wave (32 rows), d = lane ----
  float Cp = 1.f, Vp = 0.f;
  #pragma unroll 8
  for (int tt = 0; tt < 32; ++tt) {
    u32 u = cvl[cvs(wv * 32 + tt, ln)];
    __half2 hv = *(const __half2*)&u;
    float2 f = __half22float2(hv);
    Vp = fmaf(f.x, Vp, f.y);
    Cp *= f.x;
  }
  SC[wv][ln] = Cp;
  SV[wv][ln] = Vp;
  __syncthreads();

  if (PASS == 1) {
    if (wv == 0) {
      float C = SC[0][ln], V = SV[0][ln];
      #pragma unroll
      for (int s = 1; s < 4; ++s) {
        V = fmaf(SC[s][ln], V, SV[s][ln]);
        C *= SC[s][ln];
      }
      int idx = ck * DI + nt * 64 + ln;
      Cc[idx] = C;
      He[idx] = V;
    }
  } else {
    // carry-in for this wave's segment
    float h = Hin[ck * DI + nt * 64 + ln];
    if (wv >= 1) h = fmaf(SC[0][ln], h, SV[0][ln]);
    if (wv >= 2) h = fmaf(SC[1][ln], h, SV[1][ln]);
    if (wv >= 3) h = fmaf(SC[2][ln], h, SV[2][ln]);
    const float wd = wcomb[nt * 64 + ln];
    // apply + in-place rotated pv store (same-wave rows: read precedes write)
    #pragma unroll 4
    for (int tt = 0; tt < 32; ++tt) {
      const int t = wv * 32 + tt;
      u32 u = cvl[cvs(t, ln)];
      __half2 hv = *(const __half2*)&u;
      float2 f = __half22float2(hv);
      h = fmaf(f.x, h, f.y);
      float pv = h * wd;
      cvl[t * 64 + ((ln + t) & 63)] = __float_as_uint(pv);
    }
    __syncthreads();
    // row reduction: 2 threads per row, rotated (conflict-free) reads
    const int row = tid >> 1, half = tid & 1;
    float s = 0.f;
    #pragma unroll 8
    for (int jj = 0; jj < 32; ++jj) {
      int idx = (half * 32 + jj + row) & 63;
      s += __uint_as_float(cvl[row * 64 + idx]);
    }
    s += __shfl_xor(s, 1);
    if (half == 0) part[(size_t)nt * M + m0 + row] = s;
  }
}

// ---------------- cross-chunk carry scan ----------------
__global__ __launch_bounds__(768) void scan_carry(const float* __restrict__ Cc,
                                                  const float* __restrict__ He,
                                                  float* __restrict__ Hin) {
  const int b = blockIdx.x, d = threadIdx.x;
  float carry = 0.f;
  for (int q = 0; q < NCHB; ++q) {
    int idx = (b * NCHB + q) * DI + d;
    Hin[idx] = carry;
    carry = fmaf(Cc[idx], carry, He[idx]);
  }
}

// ---------------- final: sum 12 d-tile partials ----------------
__global__ __launch_bounds__(256) void reduce12(const float* __restrict__ part,
                                                float* __restrict__ out) {
  int i = blockIdx.x * 256 + threadIdx.x;     // 65536
  float s = 0.f;
  #pragma unroll
  for (int w = 0; w < DTILES; ++w) s += part[(size_t)w * M + i];
  out[i] = s;
}

// ---------------- launcher ----------------
extern "C" void kernel_launch(void* const* d_in, const int* in_sizes, int n_in,
                              void* d_out, int out_size, void* d_ws, size_t ws_size,
                              hipStream_t stream) {
  const float* x    = (const float*)d_in[0];
  const float* Win  = (const float*)d_in[1];
  const float* Whg  = (const float*)d_in[2];
  const float* Wout = (const float*)d_in[3];
  const float* Wfin = (const float*)d_in[4];
  float* out = (float*)d_out;
  char* ws = (char*)d_ws;

  u16*   xb   = (u16*)(ws + OFF_XB);
  u16*   B2c  = (u16*)(ws + OFF_B2C);
  float* wc   = (float*)(ws + OFF_WC);
  float* Cc   = (float*)(ws + OFF_CC);
  float* He   = (float*)(ws + OFF_HE);
  float* Hin  = (float*)(ws + OFF_HIN);
  float* part = (float*)(ws + OFF_PART);

  prep_xb   <<<2048, 256, 0, stream>>>(x, xb);
  prep_b2c  <<<384,  256, 0, stream>>>(Win, Whg, B2c);
  prep_wcomb<<<192,  256, 0, stream>>>(Wout, Wfin, wc);
  fused_gemm_scan<1><<<NCHUNK * DTILES, 256, 0, stream>>>(xb, B2c, Hin, wc, Cc, He, part);
  scan_carry<<<BB, DI, 0, stream>>>(Cc, He, Hin);
  fused_gemm_scan<2><<<NCHUNK * DTILES, 256, 0, stream>>>(xb, B2c, Hin, wc, Cc, He, part);
  reduce12  <<<256,  256, 0, stream>>>(part, out);
}